// Round 1
// baseline (2045.685 us; speedup 1.0000x reference)
//
#include <hip/hip_runtime.h>

typedef unsigned long long u64;
typedef unsigned int u32;

#define NROWS 32768
#define DIN   1024
#define DM    512
#define KC    1024

// ---- output float offsets (concat in reference return order) ----
#define OFF_XR   0ull          // x_recon      [32768,1024]
#define OFF_CL   33554432ull   // commit_loss  [1]
#define OFF_IDX  33554433ull   // indices      [32768] (written as float!)
#define OFF_ZE   33587201ull   // z_e          [32768,512]  (base %4==1 -> scalar access only)
#define OFF_ZQ   50364417ull   // z_q_st       [32768,512]
#define OFF_NE   67141633ull   // new_embeddings [1024,512]
#define OFF_NCS  67665921ull   // new_cluster_size [1024]
#define OFF_NEMA 67666945ull   // new_ema_embed_sum [1024,512]

// ---- workspace byte offsets (~2.8 MB total) ----
#define WS_EMBT    0ull        // float[512*1024] emb^T
#define WS_ROWMIN  2097152ull  // u64[32768]
#define WS_ZNORM   2359296ull  // float[32768]
#define WS_IDX     2490368ull  // int[32768]
#define WS_COUNTS  2621440ull  // int[1024]
#define WS_STARTS  2625536ull  // int[1024]
#define WS_OFFW    2629632ull  // int[1024]
#define WS_ROWLIST 2633728ull  // int[32768]
#define WS_CSD     2764800ull  // float[1024]
#define WS_CACC    2768896ull  // float[1]
#define WS_ENORM   2769920ull  // float[1024]

__global__ __launch_bounds__(256) void k_init(u64* __restrict__ rowmin,
                                              int* __restrict__ counts,
                                              float* __restrict__ cacc) {
  int i = blockIdx.x * 256 + threadIdx.x;       // grid = exactly 32768 threads
  rowmin[i] = ~0ull;
  if (i < KC) counts[i] = 0;
  if (i == 0) cacc[0] = 0.f;
}

__global__ __launch_bounds__(256) void k_transpose(const float* __restrict__ E,
                                                   float* __restrict__ ET) {
  __shared__ float tile[32][33];
  int tx = threadIdx.x & 31;
  int ty = threadIdx.x >> 5;                    // 0..7
  int kb = blockIdx.y * 32;                     // along K (codes)
  int db = blockIdx.x * 32;                     // along D
#pragma unroll
  for (int i = 0; i < 32; i += 8)
    tile[ty + i][tx] = E[(size_t)(kb + ty + i) * DM + db + tx];
  __syncthreads();
#pragma unroll
  for (int i = 0; i < 32; i += 8)
    ET[(size_t)(db + ty + i) * KC + kb + tx] = tile[tx][ty + i];
}

__global__ __launch_bounds__(64) void k_enorm(const float* __restrict__ E,
                                              float* __restrict__ enorm) {
  int k = blockIdx.x, t = threadIdx.x;
  float s = 0.f;
#pragma unroll
  for (int j = 0; j < 8; j++) {
    float v = E[(size_t)k * DM + t + j * 64];
    s = fmaf(v, v, s);
  }
#pragma unroll
  for (int m = 1; m < 64; m <<= 1) s += __shfl_xor(s, m, 64);
  if (t == 0) enorm[k] = s;
}

// fp32 GEMM core: 128x128 tile, BK=16, 256 threads, 8x8 per thread.
// EPI=0: C = A@B + bias (scalar stores; C may be 4B-aligned only)
// EPI=1: distance argmin epilogue: d = fmaf(-2,dot,znorm[r]) + enorm[c],
//        pack (orderable_bits(d)<<32 | c), shfl-reduce over 16 lanes, atomicMin.
template <int EPI>
__global__ __launch_bounds__(256) void k_gemm(
    const float* __restrict__ A, int lda,
    const float* __restrict__ B, int ldb,
    const float* __restrict__ bias,            // bias (EPI0) or enorm (EPI1)
    float* __restrict__ C, int ldc,
    const float* __restrict__ znorm,
    u64* __restrict__ rowmin,
    int K) {
  __shared__ float As[16][132];                // As[k][m], stride 132 -> 16B-aligned rows, bank-clean
  __shared__ float Bs[16][132];
  const int t = threadIdx.x;
  const int tx = t & 15, ty = t >> 4;
  const int rowBase = blockIdx.y * 128;
  const int colBase = blockIdx.x * 128;

  float acc[8][8];
#pragma unroll
  for (int i = 0; i < 8; i++)
#pragma unroll
    for (int j = 0; j < 8; j++) acc[i][j] = 0.f;

  for (int k0 = 0; k0 < K; k0 += 16) {
    // A tile 128x16, scalar loads (A base may be only 4B-aligned)
#pragma unroll
    for (int jj = 0; jj < 8; jj++) {
      int e = t + 256 * jj;
      int row = e >> 4, kk = e & 15;
      As[kk][row] = A[(size_t)(rowBase + row) * lda + k0 + kk];
    }
    // B tile 16x128, float4 loads (B always 16B-aligned: inputs or ws)
#pragma unroll
    for (int jj = 0; jj < 2; jj++) {
      int e = t + 256 * jj;
      int row = e >> 5, c4 = (e & 31) << 2;
      float4 v = *reinterpret_cast<const float4*>(B + (size_t)(k0 + row) * ldb + colBase + c4);
      *reinterpret_cast<float4*>(&Bs[row][c4]) = v;
    }
    __syncthreads();
#pragma unroll
    for (int k = 0; k < 16; k++) {
      float4 a0 = *reinterpret_cast<const float4*>(&As[k][ty * 4]);
      float4 a1 = *reinterpret_cast<const float4*>(&As[k][ty * 4 + 64]);
      float4 b0 = *reinterpret_cast<const float4*>(&Bs[k][tx * 4]);
      float4 b1 = *reinterpret_cast<const float4*>(&Bs[k][tx * 4 + 64]);
      float av[8] = {a0.x, a0.y, a0.z, a0.w, a1.x, a1.y, a1.z, a1.w};
      float bv[8] = {b0.x, b0.y, b0.z, b0.w, b1.x, b1.y, b1.z, b1.w};
#pragma unroll
      for (int i = 0; i < 8; i++)
#pragma unroll
        for (int j = 0; j < 8; j++)
          acc[i][j] = fmaf(av[i], bv[j], acc[i][j]);
    }
    __syncthreads();
  }

  if (EPI == 0) {
#pragma unroll
    for (int ib = 0; ib < 2; ib++)
#pragma unroll
      for (int i = 0; i < 4; i++) {
        size_t r = rowBase + ty * 4 + ib * 64 + i;
#pragma unroll
        for (int jb = 0; jb < 2; jb++)
#pragma unroll
          for (int j = 0; j < 4; j++) {
            int c = colBase + tx * 4 + jb * 64 + j;
            C[r * ldc + c] = acc[ib * 4 + i][jb * 4 + j] + bias[c];
          }
      }
  } else {
    float en[8];
#pragma unroll
    for (int jb = 0; jb < 2; jb++)
#pragma unroll
      for (int j = 0; j < 4; j++)
        en[jb * 4 + j] = bias[colBase + tx * 4 + jb * 64 + j];
#pragma unroll
    for (int ib = 0; ib < 2; ib++)
#pragma unroll
      for (int i = 0; i < 4; i++) {
        int r = rowBase + ty * 4 + ib * 64 + i;
        float zn = znorm[r];
        u64 best = ~0ull;
#pragma unroll
        for (int jb = 0; jb < 2; jb++)
#pragma unroll
          for (int j = 0; j < 4; j++) {
            int c = colBase + tx * 4 + jb * 64 + j;
            // replicate ref rounding tree: (znorm - 2*dot) + enorm
            float t1 = fmaf(-2.0f, acc[ib * 4 + i][jb * 4 + j], zn);
            float d = t1 + en[jb * 4 + j];
            u32 kb = __float_as_uint(d);
            kb = (kb & 0x80000000u) ? ~kb : (kb | 0x80000000u);  // monotone float->uint
            u64 p = ((u64)kb << 32) | (u32)c;
            best = p < best ? p : best;
          }
          // lanes 0..15 of each 16-lane group share ty (same rows): butterfly over tx
#pragma unroll
        for (int m = 1; m < 16; m <<= 1) {
          u64 o = __shfl_xor(best, m, 64);
          best = o < best ? o : best;
        }
        if (tx == 0) atomicMin(rowmin + r, best);
      }
  }
}

__global__ __launch_bounds__(128) void k_ln(float* __restrict__ ze,
                                            const float* __restrict__ g,
                                            const float* __restrict__ b,
                                            float* __restrict__ znorm) {
  int r = blockIdx.x, t = threadIdx.x;
  float* row = ze + (size_t)r * DM;
  float v[4];
  float s = 0.f, sq = 0.f;
#pragma unroll
  for (int j = 0; j < 4; j++) {
    v[j] = row[t + j * 128];
    s += v[j];
    sq = fmaf(v[j], v[j], sq);
  }
#pragma unroll
  for (int m = 1; m < 64; m <<= 1) {
    s += __shfl_xor(s, m, 64);
    sq += __shfl_xor(sq, m, 64);
  }
  __shared__ float sh[4];
  if ((t & 63) == 0) { sh[(t >> 6) * 2] = s; sh[(t >> 6) * 2 + 1] = sq; }
  __syncthreads();
  s = sh[0] + sh[2];
  sq = sh[1] + sh[3];
  float mu = s * (1.f / DM);
  float var = sq * (1.f / DM) - mu * mu;
  float rs = rsqrtf(var + 1e-5f);
  float zn = 0.f;
#pragma unroll
  for (int j = 0; j < 4; j++) {
    int c = t + j * 128;
    float o = (v[j] - mu) * rs * g[c] + b[c];
    row[c] = o;
    zn = fmaf(o, o, zn);
  }
#pragma unroll
  for (int m = 1; m < 64; m <<= 1) zn += __shfl_xor(zn, m, 64);
  __syncthreads();
  if ((t & 63) == 0) sh[t >> 6] = zn;
  __syncthreads();
  if (t == 0) znorm[r] = sh[0] + sh[1];
}

__global__ __launch_bounds__(128) void k_gather(const u64* __restrict__ rowmin,
                                                const float* __restrict__ E,
                                                float* __restrict__ out,
                                                int* __restrict__ idxws,
                                                int* __restrict__ counts,
                                                float* __restrict__ cacc) {
  int r = blockIdx.x, t = threadIdx.x;
  int idx = (int)(u32)(rowmin[r] & 0xffffffffull);
  const float* ze = out + OFF_ZE + (size_t)r * DM;
  float* zq = out + OFF_ZQ + (size_t)r * DM;
  const float* e = E + (size_t)idx * DM;
  float loc = 0.f;
#pragma unroll
  for (int j = 0; j < 4; j++) {
    int c = t + j * 128;
    float z = ze[c], q = e[c];
    zq[c] = q;                                  // z_q_st == z_q numerically
    float d = z - q;
    loc = fmaf(d, d, loc);
  }
#pragma unroll
  for (int m = 1; m < 64; m <<= 1) loc += __shfl_xor(loc, m, 64);
  __shared__ float sh[2];
  if ((t & 63) == 0) sh[t >> 6] = loc;
  __syncthreads();
  if (t == 0) {
    atomicAdd(cacc, sh[0] + sh[1]);
    atomicAdd(counts + idx, 1);
    out[OFF_IDX + r] = (float)idx;              // indices compared as float32
    idxws[r] = idx;
  }
}

__global__ __launch_bounds__(1024) void k_scan(const int* __restrict__ counts,
                                               const float* __restrict__ cs_in,
                                               float* __restrict__ out,
                                               int* __restrict__ starts,
                                               int* __restrict__ offw,
                                               float* __restrict__ csd,
                                               const float* __restrict__ cacc) {
  __shared__ float f[1024];
  __shared__ int ib[1024];
  int t = threadIdx.x;
  int cnt = counts[t];
  float ncs = 0.99f * cs_in[t] + 0.01f * (float)cnt;
  out[OFF_NCS + t] = ncs;
  f[t] = ncs;
  __syncthreads();
  for (int s = 512; s > 0; s >>= 1) {
    if (t < s) f[t] += f[t + s];
    __syncthreads();
  }
  float n = f[0];
  csd[t] = (ncs + 1e-5f) / (n + (float)KC * 1e-5f) * n;
  ib[t] = cnt;
  __syncthreads();
  for (int s = 1; s < 1024; s <<= 1) {          // Hillis-Steele inclusive scan
    int y = (t >= s) ? ib[t - s] : 0;
    __syncthreads();
    ib[t] += y;
    __syncthreads();
  }
  int excl = ib[t] - cnt;
  starts[t] = excl;
  offw[t] = excl;
  if (t == 0) out[OFF_CL] = cacc[0] * (1.f / ((float)NROWS * (float)DM));
}

__global__ __launch_bounds__(256) void k_scatter(const int* __restrict__ idxws,
                                                 int* __restrict__ offw,
                                                 int* __restrict__ rowlist) {
  int r = blockIdx.x * 256 + threadIdx.x;
  int idx = idxws[r];
  int pos = atomicAdd(offw + idx, 1);
  rowlist[pos] = r;
}

__global__ __launch_bounds__(128) void k_codesum(const int* __restrict__ starts,
                                                 const int* __restrict__ counts,
                                                 const int* __restrict__ rowlist,
                                                 const float* __restrict__ ema_in,
                                                 const float* __restrict__ csd,
                                                 float* __restrict__ out) {
  int k = blockIdx.x, t = threadIdx.x;
  int s0 = starts[k], cnt = counts[k];
  float a0 = 0.f, a1 = 0.f, a2 = 0.f, a3 = 0.f;
  const float* zeb = out + OFF_ZE;
  for (int i = 0; i < cnt; i++) {
    int r = rowlist[s0 + i];
    const float* z = zeb + (size_t)r * DM;
    a0 += z[t];
    a1 += z[t + 128];
    a2 += z[t + 256];
    a3 += z[t + 384];
  }
  float cs = csd[k];
  float sum[4] = {a0, a1, a2, a3};
#pragma unroll
  for (int j = 0; j < 4; j++) {
    int c = t + j * 128;
    float e = 0.99f * ema_in[(size_t)k * DM + c] + 0.01f * sum[j];
    out[OFF_NEMA + (size_t)k * DM + c] = e;
    out[OFF_NE + (size_t)k * DM + c] = e / cs;
  }
}

extern "C" void kernel_launch(void* const* d_in, const int* in_sizes, int n_in,
                              void* d_out, int out_size, void* d_ws, size_t ws_size,
                              hipStream_t stream) {
  (void)in_sizes; (void)n_in; (void)out_size; (void)ws_size;
  const float* x = (const float*)d_in[0];
  const float* enc_w = (const float*)d_in[1];
  const float* enc_b = (const float*)d_in[2];
  const float* ln_g = (const float*)d_in[3];
  const float* ln_b = (const float*)d_in[4];
  const float* dec_w = (const float*)d_in[5];
  const float* dec_b = (const float*)d_in[6];
  const float* emb = (const float*)d_in[7];
  const float* cs_in = (const float*)d_in[8];
  const float* ema_in = (const float*)d_in[9];
  float* out = (float*)d_out;
  char* ws = (char*)d_ws;
  float* embT = (float*)(ws + WS_EMBT);
  u64* rowmin = (u64*)(ws + WS_ROWMIN);
  float* znorm = (float*)(ws + WS_ZNORM);
  int* idxws = (int*)(ws + WS_IDX);
  int* counts = (int*)(ws + WS_COUNTS);
  int* starts = (int*)(ws + WS_STARTS);
  int* offw = (int*)(ws + WS_OFFW);
  int* rowlist = (int*)(ws + WS_ROWLIST);
  float* csd = (float*)(ws + WS_CSD);
  float* cacc = (float*)(ws + WS_CACC);
  float* enorm = (float*)(ws + WS_ENORM);

  k_init<<<dim3(NROWS / 256), dim3(256), 0, stream>>>(rowmin, counts, cacc);
  k_transpose<<<dim3(DM / 32, KC / 32), dim3(256), 0, stream>>>(emb, embT);
  k_enorm<<<dim3(KC), dim3(64), 0, stream>>>(emb, enorm);
  // encoder GEMM: h = x @ enc_w + enc_b  -> z_e region (pre-LN)
  k_gemm<0><<<dim3(DM / 128, NROWS / 128), dim3(256), 0, stream>>>(
      x, DIN, enc_w, DM, enc_b, out + OFF_ZE, DM, nullptr, nullptr, DIN);
  // LayerNorm in-place + per-row ||z_e||^2
  k_ln<<<dim3(NROWS), dim3(128), 0, stream>>>(out + OFF_ZE, ln_g, ln_b, znorm);
  // distance GEMM + fused argmin
  k_gemm<1><<<dim3(KC / 128, NROWS / 128), dim3(256), 0, stream>>>(
      out + OFF_ZE, DM, embT, KC, enorm, nullptr, 0, znorm, rowmin, DM);
  // gather z_q, commit-loss partials, histogram, indices
  k_gather<<<dim3(NROWS), dim3(128), 0, stream>>>(rowmin, emb, out, idxws, counts, cacc);
  // cluster-size EMA, normalizer, prefix sums, commit finalize
  k_scan<<<dim3(1), dim3(1024), 0, stream>>>(counts, cs_in, out, starts, offw, csd, cacc);
  // bucket rows by code
  k_scatter<<<dim3(NROWS / 256), dim3(256), 0, stream>>>(idxws, offw, rowlist);
  // per-code segment sum -> new_ema, new_embeddings
  k_codesum<<<dim3(KC), dim3(128), 0, stream>>>(starts, counts, rowlist, ema_in, csd, out);
  // decoder GEMM: x_recon = z_q_st @ dec_w + dec_b
  k_gemm<0><<<dim3(DIN / 128, NROWS / 128), dim3(256), 0, stream>>>(
      out + OFF_ZQ, DM, dec_w, DIN, dec_b, out + OFF_XR, DIN, nullptr, nullptr, DM);
}

// Round 2
// 890.831 us; speedup vs baseline: 2.2964x; 2.2964x over previous
//
#include <hip/hip_runtime.h>

typedef unsigned long long u64;
typedef unsigned int u32;
typedef _Float16 f16;
typedef _Float16 f16x8 __attribute__((ext_vector_type(8)));
typedef float f32x4 __attribute__((ext_vector_type(4)));

#define MFMA16(a, b, c) __builtin_amdgcn_mfma_f32_16x16x32_f16(a, b, c, 0, 0, 0)

#define NROWS 32768
#define DIN   1024
#define DM    512
#define KC    1024
#define SPLIT_SC  1024.0f
#define SPLIT_INV 0.0009765625f

// ---- output float offsets (concat in reference return order) ----
#define OFF_XR   0ull          // x_recon      [32768,1024]
#define OFF_CL   33554432ull   // commit_loss  [1]
#define OFF_IDX  33554433ull   // indices      [32768] (written as float!)
#define OFF_ZE   33587201ull   // z_e          [32768,512]  (base %4==1 -> scalar access only)
#define OFF_ZQ   50364417ull   // z_q_st       [32768,512]
#define OFF_NE   67141633ull   // new_embeddings [1024,512]
#define OFF_NCS  67665921ull   // new_cluster_size [1024]
#define OFF_NEMA 67666945ull   // new_ema_embed_sum [1024,512]

// ---- workspace byte offsets ----
// low region (shared with fallback path)
#define WS_EMBT    0ull        // float[512*1024] emb^T (fallback only)
#define WS_ROWMIN  2097152ull  // u64[32768] (fallback only)
#define WS_ZNORM   2359296ull  // float[32768] (fallback only)
#define WS_IDX     2490368ull  // int[32768]
#define WS_COUNTS  2621440ull  // int[1024]
#define WS_STARTS  2625536ull  // int[1024]
#define WS_OFFW    2629632ull  // int[1024]
#define WS_ROWLIST 2633728ull  // int[32768]
#define WS_CSD     2764800ull  // float[1024]
#define WS_CACC    2768896ull  // float[1]
#define WS_ENORM   2769920ull  // float[1024]
// new-path region (>= 4MB)
#define WS2_ZQ16   (4ull<<20)   // f16[32768*512]  32MB
#define WS2_WT1    (36ull<<20)  // f16[512*1024]   1MB  enc_w^T hi
#define WS2_WT2    (37ull<<20)  // f16[512*1024]   1MB  enc_w^T lo*1024
#define WS2_DT     (38ull<<20)  // f16[1024*512]   1MB  dec_w^T
#define WS2_E1     (39ull<<20)  // f16[1024*512]   1MB  emb hi
#define WS2_E2     (40ull<<20)  // f16[1024*512]   1MB  emb lo*1024
#define WS2_NEED   (41ull<<20)

// ============================================================================
// shared helpers for MFMA tiles: plane = f16[128 rows][64 k], 16B-chunk XOR swizzle
// ============================================================================
__device__ inline f16x8 ldfrag(const f16* p, int row, int kc) {
  return *(const f16x8*)(p + row * 64 + ((kc ^ (row & 7)) << 3));
}
__device__ inline void stg(f16* lds, int r, int c, f16x8 v) {
  *(f16x8*)(lds + r * 64 + ((c ^ (r & 7)) << 3)) = v;
}

// ============================================================================
// prep kernels
// ============================================================================
__global__ __launch_bounds__(256) void k_init2(int* __restrict__ counts,
                                               float* __restrict__ cacc) {
  int i = blockIdx.x * 256 + threadIdx.x;
  if (i < KC) counts[i] = 0;
  if (i == 0) cacc[0] = 0.f;
}

// transpose W[K][N] -> out[N][K] in f16; o2 (optional) gets scaled residual plane
__global__ __launch_bounds__(256) void k_prept(const float* __restrict__ W,
                                               f16* __restrict__ o1,
                                               f16* __restrict__ o2,
                                               int K, int N) {
  __shared__ float tile[32][33];
  int tx = threadIdx.x & 31, ty = threadIdx.x >> 5;
  int nb = blockIdx.x * 32, kb = blockIdx.y * 32;
#pragma unroll
  for (int i = 0; i < 32; i += 8)
    tile[ty + i][tx] = W[(size_t)(kb + ty + i) * N + nb + tx];
  __syncthreads();
#pragma unroll
  for (int i = 0; i < 32; i += 8) {
    float v = tile[tx][ty + i];
    f16 h = (f16)v;
    size_t o = (size_t)(nb + ty + i) * K + kb + tx;
    o1[o] = h;
    if (o2) o2[o] = (f16)((v - (float)h) * SPLIT_SC);
  }
}

__global__ __launch_bounds__(256) void k_prepe(const float* __restrict__ E,
                                               f16* __restrict__ e1,
                                               f16* __restrict__ e2) {
  int tid = blockIdx.x * 256 + threadIdx.x;
  for (int i = tid; i < KC * DM; i += 131072) {
    float v = E[i];
    f16 h = (f16)v;
    e1[i] = h;
    e2[i] = (f16)((v - (float)h) * SPLIT_SC);
  }
}

__global__ __launch_bounds__(64) void k_enorm(const float* __restrict__ E,
                                              float* __restrict__ enorm) {
  int k = blockIdx.x, t = threadIdx.x;
  float s = 0.f;
#pragma unroll
  for (int j = 0; j < 8; j++) {
    float v = E[(size_t)k * DM + t + j * 64];
    s = fmaf(v, v, s);
  }
#pragma unroll
  for (int m = 1; m < 64; m <<= 1) s += __shfl_xor(s, m, 64);
  if (t == 0) enorm[k] = s;
}

// ============================================================================
// encoder GEMM: h = x @ enc_w + enc_b, split-f16 3-product (fp32-grade accuracy)
// tile 128x128, BK=64, 512 thr (8 waves 2x4), wave tile 64x32
// ============================================================================
__global__ __launch_bounds__(512) void k_genc(const float* __restrict__ x,
                                              const f16* __restrict__ wt1,
                                              const f16* __restrict__ wt2,
                                              const float* __restrict__ bias,
                                              float* __restrict__ dst) {
  __shared__ __align__(16) f16 A1[128 * 64], A2[128 * 64], B1[128 * 64], B2[128 * 64];
  int t = threadIdx.x, lane = t & 63, wid = t >> 6;
  int wm = wid >> 2, wn = wid & 3;
  int m0 = blockIdx.y * 128, n0 = blockIdx.x * 128;
  f32x4 accA[4][2] = {}, accB[4][2] = {};
  int sr = t >> 2, sq = t & 3;

  for (int k0 = 0; k0 < DIN; k0 += 64) {
    {  // A: x fp32 -> split f16 planes
      const float* s = x + (size_t)(m0 + sr) * DIN + k0 + sq * 16;
      f16 h1[16], h2[16];
#pragma unroll
      for (int i = 0; i < 16; i += 4) {
        float4 v = *(const float4*)(s + i);
        float a[4] = {v.x, v.y, v.z, v.w};
#pragma unroll
        for (int j = 0; j < 4; j++) {
          f16 h = (f16)a[j];
          h1[i + j] = h;
          h2[i + j] = (f16)((a[j] - (float)h) * SPLIT_SC);
        }
      }
      stg(A1, sr, 2 * sq, *(f16x8*)&h1[0]);
      stg(A1, sr, 2 * sq + 1, *(f16x8*)&h1[8]);
      stg(A2, sr, 2 * sq, *(f16x8*)&h2[0]);
      stg(A2, sr, 2 * sq + 1, *(f16x8*)&h2[8]);
    }
    {  // B: pre-split enc_w^T planes
      const f16* s1 = wt1 + (size_t)(n0 + sr) * DIN + k0 + sq * 16;
      const f16* s2 = wt2 + (size_t)(n0 + sr) * DIN + k0 + sq * 16;
      stg(B1, sr, 2 * sq, *(const f16x8*)s1);
      stg(B1, sr, 2 * sq + 1, *(const f16x8*)(s1 + 8));
      stg(B2, sr, 2 * sq, *(const f16x8*)s2);
      stg(B2, sr, 2 * sq + 1, *(const f16x8*)(s2 + 8));
    }
    __syncthreads();
#pragma unroll
    for (int kk = 0; kk < 2; kk++) {
      f16x8 a1f[4], a2f[4], b1f[2], b2f[2];
      int kc = kk * 4 + (lane >> 4);
#pragma unroll
      for (int m = 0; m < 4; m++) {
        int row = wm * 64 + m * 16 + (lane & 15);
        a1f[m] = ldfrag(A1, row, kc);
        a2f[m] = ldfrag(A2, row, kc);
      }
#pragma unroll
      for (int n = 0; n < 2; n++) {
        int row = wn * 32 + n * 16 + (lane & 15);
        b1f[n] = ldfrag(B1, row, kc);
        b2f[n] = ldfrag(B2, row, kc);
      }
#pragma unroll
      for (int m = 0; m < 4; m++)
#pragma unroll
        for (int n = 0; n < 2; n++) {
          accA[m][n] = MFMA16(a1f[m], b1f[n], accA[m][n]);
          accB[m][n] = MFMA16(a1f[m], b2f[n], accB[m][n]);
          accB[m][n] = MFMA16(a2f[m], b1f[n], accB[m][n]);
        }
    }
    __syncthreads();
  }
#pragma unroll
  for (int m = 0; m < 4; m++)
#pragma unroll
    for (int n = 0; n < 2; n++)
#pragma unroll
      for (int j = 0; j < 4; j++) {
        int row = m0 + wm * 64 + m * 16 + (lane >> 4) * 4 + j;
        int col = n0 + wn * 32 + n * 16 + (lane & 15);
        dst[(size_t)row * DM + col] = accA[m][n][j] + SPLIT_INV * accB[m][n][j] + bias[col];
      }
}

// ============================================================================
// decoder GEMM: x_recon = z_q(f16) @ dec_w^T(f16) + dec_b, 1-pass f16
// ============================================================================
__global__ __launch_bounds__(512) void k_gdec(const f16* __restrict__ zq16,
                                              const f16* __restrict__ dT,
                                              const float* __restrict__ bias,
                                              float* __restrict__ dst) {
  __shared__ __align__(16) f16 A1[128 * 64], B1[128 * 64];
  int t = threadIdx.x, lane = t & 63, wid = t >> 6;
  int wm = wid >> 2, wn = wid & 3;
  int m0 = blockIdx.y * 128, n0 = blockIdx.x * 128;
  f32x4 acc[4][2] = {};
  int sr = t >> 2, sq = t & 3;

  for (int k0 = 0; k0 < DM; k0 += 64) {
    {
      const f16* s = zq16 + (size_t)(m0 + sr) * DM + k0 + sq * 16;
      stg(A1, sr, 2 * sq, *(const f16x8*)s);
      stg(A1, sr, 2 * sq + 1, *(const f16x8*)(s + 8));
      const f16* sb = dT + (size_t)(n0 + sr) * DM + k0 + sq * 16;
      stg(B1, sr, 2 * sq, *(const f16x8*)sb);
      stg(B1, sr, 2 * sq + 1, *(const f16x8*)(sb + 8));
    }
    __syncthreads();
#pragma unroll
    for (int kk = 0; kk < 2; kk++) {
      f16x8 a1f[4], b1f[2];
      int kc = kk * 4 + (lane >> 4);
#pragma unroll
      for (int m = 0; m < 4; m++) a1f[m] = ldfrag(A1, wm * 64 + m * 16 + (lane & 15), kc);
#pragma unroll
      for (int n = 0; n < 2; n++) b1f[n] = ldfrag(B1, wn * 32 + n * 16 + (lane & 15), kc);
#pragma unroll
      for (int m = 0; m < 4; m++)
#pragma unroll
        for (int n = 0; n < 2; n++) acc[m][n] = MFMA16(a1f[m], b1f[n], acc[m][n]);
    }
    __syncthreads();
  }
#pragma unroll
  for (int m = 0; m < 4; m++)
#pragma unroll
    for (int n = 0; n < 2; n++)
#pragma unroll
      for (int j = 0; j < 4; j++) {
        int row = m0 + wm * 64 + m * 16 + (lane >> 4) * 4 + j;
        int col = n0 + wn * 32 + n * 16 + (lane & 15);
        dst[(size_t)row * DIN + col] = acc[m][n][j] + bias[col];
      }
}

// ============================================================================
// distance + argmin + gather, fused. One block = 128 rows x all 1024 codes.
// split-f16 3-product => fp32-grade scores; per-row argmin in LDS.
// ============================================================================
__global__ __launch_bounds__(512) void k_dist(const f16* __restrict__ z1,
                                              const f16* __restrict__ z2,
                                              const f16* __restrict__ e1,
                                              const f16* __restrict__ e2,
                                              const float* __restrict__ enorm,
                                              const float* __restrict__ emb,
                                              float* __restrict__ out,
                                              int* __restrict__ idxws,
                                              int* __restrict__ counts,
                                              float* __restrict__ cacc,
                                              f16* __restrict__ zq16) {
  __shared__ __align__(16) f16 A1[128 * 64], A2[128 * 64], B1[128 * 64], B2[128 * 64];
  __shared__ float enorm_s[KC];
  __shared__ u64 rowmin_s[128];
  __shared__ int idx_s[128];
  __shared__ float red_s[8];
  int t = threadIdx.x, lane = t & 63, wid = t >> 6;
  int wm = wid >> 2, wn = wid & 3;
  int r0 = blockIdx.x * 128;
  int sr = t >> 2, sq = t & 3;

  for (int i = t; i < KC; i += 512) enorm_s[i] = enorm[i];
  if (t < 128) rowmin_s[t] = ~0ull;
  __syncthreads();

  for (int ct = 0; ct < KC / 128; ct++) {
    f32x4 accA[4][2] = {}, accB[4][2] = {};
    int c0 = ct * 128;
    for (int k0 = 0; k0 < DM; k0 += 64) {
      {
        const f16* sa1 = z1 + (size_t)(r0 + sr) * DM + k0 + sq * 16;
        const f16* sa2 = z2 + (size_t)(r0 + sr) * DM + k0 + sq * 16;
        stg(A1, sr, 2 * sq, *(const f16x8*)sa1);
        stg(A1, sr, 2 * sq + 1, *(const f16x8*)(sa1 + 8));
        stg(A2, sr, 2 * sq, *(const f16x8*)sa2);
        stg(A2, sr, 2 * sq + 1, *(const f16x8*)(sa2 + 8));
        const f16* sb1 = e1 + (size_t)(c0 + sr) * DM + k0 + sq * 16;
        const f16* sb2 = e2 + (size_t)(c0 + sr) * DM + k0 + sq * 16;
        stg(B1, sr, 2 * sq, *(const f16x8*)sb1);
        stg(B1, sr, 2 * sq + 1, *(const f16x8*)(sb1 + 8));
        stg(B2, sr, 2 * sq, *(const f16x8*)sb2);
        stg(B2, sr, 2 * sq + 1, *(const f16x8*)(sb2 + 8));
      }
      __syncthreads();
#pragma unroll
      for (int kk = 0; kk < 2; kk++) {
        f16x8 a1f[4], a2f[4], b1f[2], b2f[2];
        int kc = kk * 4 + (lane >> 4);
#pragma unroll
        for (int m = 0; m < 4; m++) {
          int row = wm * 64 + m * 16 + (lane & 15);
          a1f[m] = ldfrag(A1, row, kc);
          a2f[m] = ldfrag(A2, row, kc);
        }
#pragma unroll
        for (int n = 0; n < 2; n++) {
          int row = wn * 32 + n * 16 + (lane & 15);
          b1f[n] = ldfrag(B1, row, kc);
          b2f[n] = ldfrag(B2, row, kc);
        }
#pragma unroll
        for (int m = 0; m < 4; m++)
#pragma unroll
          for (int n = 0; n < 2; n++) {
            accA[m][n] = MFMA16(a1f[m], b1f[n], accA[m][n]);
            accB[m][n] = MFMA16(a1f[m], b2f[n], accB[m][n]);
            accB[m][n] = MFMA16(a2f[m], b1f[n], accB[m][n]);
          }
      }
      __syncthreads();
    }
    // score + per-row argmin for this col-tile
#pragma unroll
    for (int m = 0; m < 4; m++)
#pragma unroll
      for (int j = 0; j < 4; j++) {
        int r_l = wm * 64 + m * 16 + (lane >> 4) * 4 + j;
        u64 best = ~0ull;
#pragma unroll
        for (int n = 0; n < 2; n++) {
          int col = c0 + wn * 32 + n * 16 + (lane & 15);
          float dot = accA[m][n][j] + SPLIT_INV * accB[m][n][j];
          float s = fmaf(-2.0f, dot, enorm_s[col]);
          u32 kb = __float_as_uint(s);
          kb = (kb & 0x80000000u) ? ~kb : (kb | 0x80000000u);
          u64 p = ((u64)kb << 32) | (u32)col;
          best = p < best ? p : best;
        }
#pragma unroll
        for (int msk = 1; msk < 16; msk <<= 1) {
          u64 o = __shfl_xor(best, msk, 64);
          best = o < best ? o : best;
        }
        if ((lane & 15) == 0) atomicMin(&rowmin_s[r_l], best);
      }
    __syncthreads();
  }

  // final: indices, histogram, gather z_q (fp32 + f16), commit partial
  if (t < 128) {
    int idx = (int)(u32)(rowmin_s[t] & 0xffffffffull);
    int R = r0 + t;
    out[OFF_IDX + R] = (float)idx;
    idxws[R] = idx;
    atomicAdd(counts + idx, 1);
    idx_s[t] = idx;
  }
  __syncthreads();
  float loc = 0.f;
  {
    int r = t >> 2, q = t & 3;
    int R = r0 + r;
    int idx = idx_s[r];
    const float* e = emb + (size_t)idx * DM + q * 128;
    const float* z = out + OFF_ZE + (size_t)R * DM + q * 128;
    float* zq = out + OFF_ZQ + (size_t)R * DM + q * 128;
    f16* zp = zq16 + (size_t)R * DM + q * 128;
    for (int i = 0; i < 128; i += 4) {
      float4 ev = *(const float4*)(e + i);
      float a[4] = {ev.x, ev.y, ev.z, ev.w};
#pragma unroll
      for (int jj = 0; jj < 4; jj++) {
        zq[i + jj] = a[jj];
        zp[i + jj] = (f16)a[jj];
        float d = z[i + jj] - a[jj];
        loc = fmaf(d, d, loc);
      }
    }
  }
#pragma unroll
  for (int m = 1; m < 64; m <<= 1) loc += __shfl_xor(loc, m, 64);
  if (lane == 0) red_s[wid] = loc;
  __syncthreads();
  if (t == 0) {
    float s = 0.f;
#pragma unroll
    for (int i = 0; i < 8; i++) s += red_s[i];
    atomicAdd(cacc, s);
  }
}

// ============================================================================
// LayerNorm (wave per row) + f16 split planes of z_e
// ============================================================================
__global__ __launch_bounds__(256) void k_ln2(float* __restrict__ ze,
                                             const float* __restrict__ g,
                                             const float* __restrict__ b,
                                             f16* __restrict__ z1,
                                             f16* __restrict__ z2) {
  int t = threadIdx.x, lane = t & 63, wid = t >> 6;
  int R = blockIdx.x * 4 + wid;
  float* row = ze + (size_t)R * DM;
  float v[8];
  float s = 0.f, sq = 0.f;
#pragma unroll
  for (int j = 0; j < 8; j++) {
    v[j] = row[lane + j * 64];
    s += v[j];
    sq = fmaf(v[j], v[j], sq);
  }
#pragma unroll
  for (int m = 1; m < 64; m <<= 1) {
    s += __shfl_xor(s, m, 64);
    sq += __shfl_xor(sq, m, 64);
  }
  float mu = s * (1.f / DM);
  float var = sq * (1.f / DM) - mu * mu;
  float rs = rsqrtf(var + 1e-5f);
#pragma unroll
  for (int j = 0; j < 8; j++) {
    int c = lane + j * 64;
    float o = (v[j] - mu) * rs * g[c] + b[c];
    row[c] = o;
    f16 h = (f16)o;
    z1[(size_t)R * DM + c] = h;
    z2[(size_t)R * DM + c] = (f16)((o - (float)h) * SPLIT_SC);
  }
}

// ============================================================================
// EMA tail (unchanged from round 1)
// ============================================================================
__global__ __launch_bounds__(1024) void k_scan(const int* __restrict__ counts,
                                               const float* __restrict__ cs_in,
                                               float* __restrict__ out,
                                               int* __restrict__ starts,
                                               int* __restrict__ offw,
                                               float* __restrict__ csd,
                                               const float* __restrict__ cacc) {
  __shared__ float f[1024];
  __shared__ int ib[1024];
  int t = threadIdx.x;
  int cnt = counts[t];
  float ncs = 0.99f * cs_in[t] + 0.01f * (float)cnt;
  out[OFF_NCS + t] = ncs;
  f[t] = ncs;
  __syncthreads();
  for (int s = 512; s > 0; s >>= 1) {
    if (t < s) f[t] += f[t + s];
    __syncthreads();
  }
  float n = f[0];
  csd[t] = (ncs + 1e-5f) / (n + (float)KC * 1e-5f) * n;
  ib[t] = cnt;
  __syncthreads();
  for (int s = 1; s < 1024; s <<= 1) {
    int y = (t >= s) ? ib[t - s] : 0;
    __syncthreads();
    ib[t] += y;
    __syncthreads();
  }
  int excl = ib[t] - cnt;
  starts[t] = excl;
  offw[t] = excl;
  if (t == 0) out[OFF_CL] = cacc[0] * (1.f / ((float)NROWS * (float)DM));
}

__global__ __launch_bounds__(256) void k_scatter(const int* __restrict__ idxws,
                                                 int* __restrict__ offw,
                                                 int* __restrict__ rowlist) {
  int r = blockIdx.x * 256 + threadIdx.x;
  int idx = idxws[r];
  int pos = atomicAdd(offw + idx, 1);
  rowlist[pos] = r;
}

__global__ __launch_bounds__(128) void k_codesum(const int* __restrict__ starts,
                                                 const int* __restrict__ counts,
                                                 const int* __restrict__ rowlist,
                                                 const float* __restrict__ ema_in,
                                                 const float* __restrict__ csd,
                                                 float* __restrict__ out) {
  int k = blockIdx.x, t = threadIdx.x;
  int s0 = starts[k], cnt = counts[k];
  float a0 = 0.f, a1 = 0.f, a2 = 0.f, a3 = 0.f;
  const float* zeb = out + OFF_ZE;
  for (int i = 0; i < cnt; i++) {
    int r = rowlist[s0 + i];
    const float* z = zeb + (size_t)r * DM;
    a0 += z[t];
    a1 += z[t + 128];
    a2 += z[t + 256];
    a3 += z[t + 384];
  }
  float cs = csd[k];
  float sum[4] = {a0, a1, a2, a3};
#pragma unroll
  for (int j = 0; j < 4; j++) {
    int c = t + j * 128;
    float e = 0.99f * ema_in[(size_t)k * DM + c] + 0.01f * sum[j];
    out[OFF_NEMA + (size_t)k * DM + c] = e;
    out[OFF_NE + (size_t)k * DM + c] = e / cs;
  }
}

// ============================================================================
// fallback path kernels (round-1, proven)
// ============================================================================
__global__ __launch_bounds__(256) void k_init(u64* __restrict__ rowmin,
                                              int* __restrict__ counts,
                                              float* __restrict__ cacc) {
  int i = blockIdx.x * 256 + threadIdx.x;
  rowmin[i] = ~0ull;
  if (i < KC) counts[i] = 0;
  if (i == 0) cacc[0] = 0.f;
}

__global__ __launch_bounds__(256) void k_transpose(const float* __restrict__ E,
                                                   float* __restrict__ ET) {
  __shared__ float tile[32][33];
  int tx = threadIdx.x & 31;
  int ty = threadIdx.x >> 5;
  int kb = blockIdx.y * 32;
  int db = blockIdx.x * 32;
#pragma unroll
  for (int i = 0; i < 32; i += 8)
    tile[ty + i][tx] = E[(size_t)(kb + ty + i) * DM + db + tx];
  __syncthreads();
#pragma unroll
  for (int i = 0; i < 32; i += 8)
    ET[(size_t)(db + ty + i) * KC + kb + tx] = tile[tx][ty + i];
}

template <int EPI>
__global__ __launch_bounds__(256) void k_gemm(
    const float* __restrict__ A, int lda,
    const float* __restrict__ B, int ldb,
    const float* __restrict__ bias,
    float* __restrict__ C, int ldc,
    const float* __restrict__ znorm,
    u64* __restrict__ rowmin,
    int K) {
  __shared__ float As[16][132];
  __shared__ float Bs[16][132];
  const int t = threadIdx.x;
  const int tx = t & 15, ty = t >> 4;
  const int rowBase = blockIdx.y * 128;
  const int colBase = blockIdx.x * 128;
  float acc[8][8];
#pragma unroll
  for (int i = 0; i < 8; i++)
#pragma unroll
    for (int j = 0; j < 8; j++) acc[i][j] = 0.f;
  for (int k0 = 0; k0 < K; k0 += 16) {
#pragma unroll
    for (int jj = 0; jj < 8; jj++) {
      int e = t + 256 * jj;
      int row = e >> 4, kk = e & 15;
      As[kk][row] = A[(size_t)(rowBase + row) * lda + k0 + kk];
    }
#pragma unroll
    for (int jj = 0; jj < 2; jj++) {
      int e = t + 256 * jj;
      int row = e >> 5, c4 = (e & 31) << 2;
      float4 v = *reinterpret_cast<const float4*>(B + (size_t)(k0 + row) * ldb + colBase + c4);
      *reinterpret_cast<float4*>(&Bs[row][c4]) = v;
    }
    __syncthreads();
#pragma unroll
    for (int k = 0; k < 16; k++) {
      float4 a0 = *reinterpret_cast<const float4*>(&As[k][ty * 4]);
      float4 a1 = *reinterpret_cast<const float4*>(&As[k][ty * 4 + 64]);
      float4 b0 = *reinterpret_cast<const float4*>(&Bs[k][tx * 4]);
      float4 b1 = *reinterpret_cast<const float4*>(&Bs[k][tx * 4 + 64]);
      float av[8] = {a0.x, a0.y, a0.z, a0.w, a1.x, a1.y, a1.z, a1.w};
      float bv[8] = {b0.x, b0.y, b0.z, b0.w, b1.x, b1.y, b1.z, b1.w};
#pragma unroll
      for (int i = 0; i < 8; i++)
#pragma unroll
        for (int j = 0; j < 8; j++)
          acc[i][j] = fmaf(av[i], bv[j], acc[i][j]);
    }
    __syncthreads();
  }
  if (EPI == 0) {
#pragma unroll
    for (int ib = 0; ib < 2; ib++)
#pragma unroll
      for (int i = 0; i < 4; i++) {
        size_t r = rowBase + ty * 4 + ib * 64 + i;
#pragma unroll
        for (int jb = 0; jb < 2; jb++)
#pragma unroll
          for (int j = 0; j < 4; j++) {
            int c = colBase + tx * 4 + jb * 64 + j;
            C[r * ldc + c] = acc[ib * 4 + i][jb * 4 + j] + bias[c];
          }
      }
  } else {
    float en[8];
#pragma unroll
    for (int jb = 0; jb < 2; jb++)
#pragma unroll
      for (int j = 0; j < 4; j++)
        en[jb * 4 + j] = bias[colBase + tx * 4 + jb * 64 + j];
#pragma unroll
    for (int ib = 0; ib < 2; ib++)
#pragma unroll
      for (int i = 0; i < 4; i++) {
        int r = rowBase + ty * 4 + ib * 64 + i;
        float zn = znorm[r];
        u64 best = ~0ull;
#pragma unroll
        for (int jb = 0; jb < 2; jb++)
#pragma unroll
          for (int j = 0; j < 4; j++) {
            int c = colBase + tx * 4 + jb * 64 + j;
            float t1 = fmaf(-2.0f, acc[ib * 4 + i][jb * 4 + j], zn);
            float d = t1 + en[jb * 4 + j];
            u32 kb = __float_as_uint(d);
            kb = (kb & 0x80000000u) ? ~kb : (kb | 0x80000000u);
            u64 p = ((u64)kb << 32) | (u32)c;
            best = p < best ? p : best;
          }
#pragma unroll
        for (int m = 1; m < 16; m <<= 1) {
          u64 o = __shfl_xor(best, m, 64);
          best = o < best ? o : best;
        }
        if (tx == 0) atomicMin(rowmin + r, best);
      }
  }
}

__global__ __launch_bounds__(128) void k_ln(float* __restrict__ ze,
                                            const float* __restrict__ g,
                                            const float* __restrict__ b,
                                            float* __restrict__ znorm) {
  int r = blockIdx.x, t = threadIdx.x;
  float* row = ze + (size_t)r * DM;
  float v[4];
  float s = 0.f, sq = 0.f;
#pragma unroll
  for (int j = 0; j < 4; j++) {
    v[j] = row[t + j * 128];
    s += v[j];
    sq = fmaf(v[j], v[j], sq);
  }
#pragma unroll
  for (int m = 1; m < 64; m <<= 1) {
    s += __shfl_xor(s, m, 64);
    sq += __shfl_xor(sq, m, 64);
  }
  __shared__ float sh[4];
  if ((t & 63) == 0) { sh[(t >> 6) * 2] = s; sh[(t >> 6) * 2 + 1] = sq; }
  __syncthreads();
  s = sh[0] + sh[2];
  sq = sh[1] + sh[3];
  float mu = s * (1.f / DM);
  float var = sq * (1.f / DM) - mu * mu;
  float rs = rsqrtf(var + 1e-5f);
  float zn = 0.f;
#pragma unroll
  for (int j = 0; j < 4; j++) {
    int c = t + j * 128;
    float o = (v[j] - mu) * rs * g[c] + b[c];
    row[c] = o;
    zn = fmaf(o, o, zn);
  }
#pragma unroll
  for (int m = 1; m < 64; m <<= 1) zn += __shfl_xor(zn, m, 64);
  __syncthreads();
  if ((t & 63) == 0) sh[t >> 6] = zn;
  __syncthreads();
  if (t == 0) znorm[r] = sh[0] + sh[1];
}

__global__ __launch_bounds__(128) void k_gather(const u64* __restrict__ rowmin,
                                                const float* __restrict__ E,
                                                float* __restrict__ out,
                                                int* __restrict__ idxws,
                                                int* __restrict__ counts,
                                                float* __restrict__ cacc) {
  int r = blockIdx.x, t = threadIdx.x;
  int idx = (int)(u32)(rowmin[r] & 0xffffffffull);
  const float* ze = out + OFF_ZE + (size_t)r * DM;
  float* zq = out + OFF_ZQ + (size_t)r * DM;
  const float* e = E + (size_t)idx * DM;
  float loc = 0.f;
#pragma unroll
  for (int j = 0; j < 4; j++) {
    int c = t + j * 128;
    float z = ze[c], q = e[c];
    zq[c] = q;
    float d = z - q;
    loc = fmaf(d, d, loc);
  }
#pragma unroll
  for (int m = 1; m < 64; m <<= 1) loc += __shfl_xor(loc, m, 64);
  __shared__ float sh[2];
  if ((t & 63) == 0) sh[t >> 6] = loc;
  __syncthreads();
  if (t == 0) {
    atomicAdd(cacc, sh[0] + sh[1]);
    atomicAdd(counts + idx, 1);
    out[OFF_IDX + r] = (float)idx;
    idxws[r] = idx;
  }
}

// ============================================================================
extern "C" void kernel_launch(void* const* d_in, const int* in_sizes, int n_in,
                              void* d_out, int out_size, void* d_ws, size_t ws_size,
                              hipStream_t stream) {
  (void)in_sizes; (void)n_in; (void)out_size;
  const float* x = (const float*)d_in[0];
  const float* enc_w = (const float*)d_in[1];
  const float* enc_b = (const float*)d_in[2];
  const float* ln_g = (const float*)d_in[3];
  const float* ln_b = (const float*)d_in[4];
  const float* dec_w = (const float*)d_in[5];
  const float* dec_b = (const float*)d_in[6];
  const float* emb = (const float*)d_in[7];
  const float* cs_in = (const float*)d_in[8];
  const float* ema_in = (const float*)d_in[9];
  float* out = (float*)d_out;
  char* ws = (char*)d_ws;
  int* idxws = (int*)(ws + WS_IDX);
  int* counts = (int*)(ws + WS_COUNTS);
  int* starts = (int*)(ws + WS_STARTS);
  int* offw = (int*)(ws + WS_OFFW);
  int* rowlist = (int*)(ws + WS_ROWLIST);
  float* csd = (float*)(ws + WS_CSD);
  float* cacc = (float*)(ws + WS_CACC);
  float* enorm = (float*)(ws + WS_ENORM);

  if (ws_size >= WS2_NEED + (8ull << 20)) {
    // ---- MFMA path ----
    f16* zq16 = (f16*)(ws + WS2_ZQ16);
    f16* wt1 = (f16*)(ws + WS2_WT1);
    f16* wt2 = (f16*)(ws + WS2_WT2);
    f16* dT = (f16*)(ws + WS2_DT);
    f16* e1 = (f16*)(ws + WS2_E1);
    f16* e2 = (f16*)(ws + WS2_E2);
    f16* z1 = (f16*)out;                 // scratch in x_recon region (overwritten by k_gdec)
    f16* z2 = z1 + (size_t)NROWS * DM;

    k_init2<<<dim3(4), dim3(256), 0, stream>>>(counts, cacc);
    k_prept<<<dim3(16, 32), dim3(256), 0, stream>>>(enc_w, wt1, wt2, DIN, DM);
    k_prept<<<dim3(32, 16), dim3(256), 0, stream>>>(dec_w, dT, nullptr, DM, DIN);
    k_prepe<<<dim3(512), dim3(256), 0, stream>>>(emb, e1, e2);
    k_enorm<<<dim3(KC), dim3(64), 0, stream>>>(emb, enorm);
    k_genc<<<dim3(4, 256), dim3(512), 0, stream>>>(x, wt1, wt2, enc_b, out + OFF_ZE);
    k_ln2<<<dim3(8192), dim3(256), 0, stream>>>(out + OFF_ZE, ln_g, ln_b, z1, z2);
    k_dist<<<dim3(256), dim3(512), 0, stream>>>(z1, z2, e1, e2, enorm, emb, out,
                                                idxws, counts, cacc, zq16);
    k_scan<<<dim3(1), dim3(1024), 0, stream>>>(counts, cs_in, out, starts, offw, csd, cacc);
    k_scatter<<<dim3(128), dim3(256), 0, stream>>>(idxws, offw, rowlist);
    k_codesum<<<dim3(1024), dim3(128), 0, stream>>>(starts, counts, rowlist, ema_in, csd, out);
    k_gdec<<<dim3(8, 256), dim3(512), 0, stream>>>(zq16, dT, dec_b, out + OFF_XR);
  } else {
    // ---- fallback: round-1 fp32 path ----
    float* embT = (float*)(ws + WS_EMBT);
    u64* rowmin = (u64*)(ws + WS_ROWMIN);
    float* znorm = (float*)(ws + WS_ZNORM);
    k_init<<<dim3(NROWS / 256), dim3(256), 0, stream>>>(rowmin, counts, cacc);
    k_transpose<<<dim3(DM / 32, KC / 32), dim3(256), 0, stream>>>(emb, embT);
    k_enorm<<<dim3(KC), dim3(64), 0, stream>>>(emb, enorm);
    k_gemm<0><<<dim3(DM / 128, NROWS / 128), dim3(256), 0, stream>>>(
        x, DIN, enc_w, DM, enc_b, out + OFF_ZE, DM, nullptr, nullptr, DIN);
    k_ln<<<dim3(NROWS), dim3(128), 0, stream>>>(out + OFF_ZE, ln_g, ln_b, znorm);
    k_gemm<1><<<dim3(KC / 128, NROWS / 128), dim3(256), 0, stream>>>(
        out + OFF_ZE, DM, embT, KC, enorm, nullptr, 0, znorm, rowmin, DM);
    k_gather<<<dim3(NROWS), dim3(128), 0, stream>>>(rowmin, emb, out, idxws, counts, cacc);
    k_scan<<<dim3(1), dim3(1024), 0, stream>>>(counts, cs_in, out, starts, offw, csd, cacc);
    k_scatter<<<dim3(NROWS / 256), dim3(256), 0, stream>>>(idxws, offw, rowlist);
    k_codesum<<<dim3(1024), dim3(128), 0, stream>>>(starts, counts, rowlist, ema_in, csd, out);
    k_gemm<0><<<dim3(DIN / 128, NROWS / 128), dim3(256), 0, stream>>>(
        out + OFF_ZQ, DM, dec_w, DIN, dec_b, out + OFF_XR, DIN, nullptr, nullptr, DM);
  }
}

// Round 3
// 597.416 us; speedup vs baseline: 3.4242x; 1.4911x over previous
//
#include <hip/hip_runtime.h>

typedef unsigned long long u64;
typedef unsigned int u32;
typedef _Float16 f16;
typedef _Float16 f16x8 __attribute__((ext_vector_type(8)));
typedef float f32x4 __attribute__((ext_vector_type(4)));

#define MFMA16(a, b, c) __builtin_amdgcn_mfma_f32_16x16x32_f16(a, b, c, 0, 0, 0)

#define NROWS 32768
#define DIN   1024
#define DM    512
#define KC    1024
#define SPLIT_SC  1024.0f
#define SPLIT_INV 0.0009765625f
#define CHSZ  32          // rows per partial-sum chunk
#define MAXCH 2048        // <= KC + NROWS/CHSZ

// ---- output float offsets (concat in reference return order) ----
#define OFF_XR   0ull          // x_recon      [32768,1024]
#define OFF_CL   33554432ull   // commit_loss  [1]
#define OFF_IDX  33554433ull   // indices      [32768] (written as float!)
#define OFF_ZE   33587201ull   // z_e          [32768,512]  (base %4==1 -> scalar access only)
#define OFF_ZQ   50364417ull   // z_q_st       [32768,512]
#define OFF_NE   67141633ull   // new_embeddings [1024,512]
#define OFF_NCS  67665921ull   // new_cluster_size [1024]
#define OFF_NEMA 67666945ull   // new_ema_embed_sum [1024,512]

// ---- workspace byte offsets ----
// low region (shared with fallback path)
#define WS_EMBT    0ull        // float[512*1024] emb^T (fallback only)
#define WS_ROWMIN  2097152ull  // u64[32768] (fallback only)
#define WS_ZNORM   2359296ull  // float[32768] (fallback only)
#define WS_IDX     2490368ull  // int[32768]
#define WS_COUNTS  2621440ull  // int[1024]
#define WS_STARTS  2625536ull  // int[1024]
#define WS_OFFW    2629632ull  // int[1024]
#define WS_ROWLIST 2633728ull  // int[32768]
#define WS_CSD     2764800ull  // float[1024]
#define WS_CACC    2768896ull  // float[1]
#define WS_ENORM   2769920ull  // float[1024]
// new-path region (>= 4MB)
#define WS2_ZQ16   (4ull<<20)   // f16[32768*512]  32MB
#define WS2_WT1    (36ull<<20)  // f16[512*1024]   1MB  enc_w^T hi
#define WS2_WT2    (37ull<<20)  // f16[512*1024]   1MB  enc_w^T lo*1024
#define WS2_DT     (38ull<<20)  // f16[1024*512]   1MB  dec_w^T
#define WS2_E1     (39ull<<20)  // f16[1024*512]   1MB  emb hi
#define WS2_E2     (40ull<<20)  // f16[1024*512]   1MB  emb lo*1024
// chunked segment-sum region
#define WS3_CHPFX  (41ull<<20)             // int[1025]
#define WS3_CHCODE ((41ull<<20) + 8192)    // int[2048]
#define WS3_PART   ((41ull<<20) + 65536)   // float[2048*512] = 4MB
#define WS2_NEED   (41ull<<20)

// ============================================================================
// shared helpers for MFMA tiles: plane = f16[128 rows][64 k], 16B-chunk XOR swizzle
// ============================================================================
__device__ inline f16x8 ldfrag(const f16* p, int row, int kc) {
  return *(const f16x8*)(p + row * 64 + ((kc ^ (row & 7)) << 3));
}
__device__ inline void stg(f16* lds, int r, int c, f16x8 v) {
  *(f16x8*)(lds + r * 64 + ((c ^ (r & 7)) << 3)) = v;
}

// ============================================================================
// prep kernels
// ============================================================================
__global__ __launch_bounds__(256) void k_init2(int* __restrict__ counts,
                                               float* __restrict__ cacc) {
  int i = blockIdx.x * 256 + threadIdx.x;
  if (i < KC) counts[i] = 0;
  if (i == 0) cacc[0] = 0.f;
}

// transpose W[K][N] -> out[N][K] in f16; o2 (optional) gets scaled residual plane
__global__ __launch_bounds__(256) void k_prept(const float* __restrict__ W,
                                               f16* __restrict__ o1,
                                               f16* __restrict__ o2,
                                               int K, int N) {
  __shared__ float tile[32][33];
  int tx = threadIdx.x & 31, ty = threadIdx.x >> 5;
  int nb = blockIdx.x * 32, kb = blockIdx.y * 32;
#pragma unroll
  for (int i = 0; i < 32; i += 8)
    tile[ty + i][tx] = W[(size_t)(kb + ty + i) * N + nb + tx];
  __syncthreads();
#pragma unroll
  for (int i = 0; i < 32; i += 8) {
    float v = tile[tx][ty + i];
    f16 h = (f16)v;
    size_t o = (size_t)(nb + ty + i) * K + kb + tx;
    o1[o] = h;
    if (o2) o2[o] = (f16)((v - (float)h) * SPLIT_SC);
  }
}

__global__ __launch_bounds__(256) void k_prepe(const float* __restrict__ E,
                                               f16* __restrict__ e1,
                                               f16* __restrict__ e2) {
  int tid = blockIdx.x * 256 + threadIdx.x;
  for (int i = tid; i < KC * DM; i += 131072) {
    float v = E[i];
    f16 h = (f16)v;
    e1[i] = h;
    e2[i] = (f16)((v - (float)h) * SPLIT_SC);
  }
}

__global__ __launch_bounds__(64) void k_enorm(const float* __restrict__ E,
                                              float* __restrict__ enorm) {
  int k = blockIdx.x, t = threadIdx.x;
  float s = 0.f;
#pragma unroll
  for (int j = 0; j < 8; j++) {
    float v = E[(size_t)k * DM + t + j * 64];
    s = fmaf(v, v, s);
  }
#pragma unroll
  for (int m = 1; m < 64; m <<= 1) s += __shfl_xor(s, m, 64);
  if (t == 0) enorm[k] = s;
}

// ============================================================================
// encoder GEMM: h = x @ enc_w + enc_b, split-f16 3-product (fp32-grade accuracy)
// ============================================================================
__global__ __launch_bounds__(512) void k_genc(const float* __restrict__ x,
                                              const f16* __restrict__ wt1,
                                              const f16* __restrict__ wt2,
                                              const float* __restrict__ bias,
                                              float* __restrict__ dst) {
  __shared__ __align__(16) f16 A1[128 * 64], A2[128 * 64], B1[128 * 64], B2[128 * 64];
  int t = threadIdx.x, lane = t & 63, wid = t >> 6;
  int wm = wid >> 2, wn = wid & 3;
  int m0 = blockIdx.y * 128, n0 = blockIdx.x * 128;
  f32x4 accA[4][2] = {}, accB[4][2] = {};
  int sr = t >> 2, sq = t & 3;

  for (int k0 = 0; k0 < DIN; k0 += 64) {
    {  // A: x fp32 -> split f16 planes
      const float* s = x + (size_t)(m0 + sr) * DIN + k0 + sq * 16;
      f16 h1[16], h2[16];
#pragma unroll
      for (int i = 0; i < 16; i += 4) {
        float4 v = *(const float4*)(s + i);
        float a[4] = {v.x, v.y, v.z, v.w};
#pragma unroll
        for (int j = 0; j < 4; j++) {
          f16 h = (f16)a[j];
          h1[i + j] = h;
          h2[i + j] = (f16)((a[j] - (float)h) * SPLIT_SC);
        }
      }
      stg(A1, sr, 2 * sq, *(f16x8*)&h1[0]);
      stg(A1, sr, 2 * sq + 1, *(f16x8*)&h1[8]);
      stg(A2, sr, 2 * sq, *(f16x8*)&h2[0]);
      stg(A2, sr, 2 * sq + 1, *(f16x8*)&h2[8]);
    }
    {  // B: pre-split enc_w^T planes
      const f16* s1 = wt1 + (size_t)(n0 + sr) * DIN + k0 + sq * 16;
      const f16* s2 = wt2 + (size_t)(n0 + sr) * DIN + k0 + sq * 16;
      stg(B1, sr, 2 * sq, *(const f16x8*)s1);
      stg(B1, sr, 2 * sq + 1, *(const f16x8*)(s1 + 8));
      stg(B2, sr, 2 * sq, *(const f16x8*)s2);
      stg(B2, sr, 2 * sq + 1, *(const f16x8*)(s2 + 8));
    }
    __syncthreads();
#pragma unroll
    for (int kk = 0; kk < 2; kk++) {
      f16x8 a1f[4], a2f[4], b1f[2], b2f[2];
      int kc = kk * 4 + (lane >> 4);
#pragma unroll
      for (int m = 0; m < 4; m++) {
        int row = wm * 64 + m * 16 + (lane & 15);
        a1f[m] = ldfrag(A1, row, kc);
        a2f[m] = ldfrag(A2, row, kc);
      }
#pragma unroll
      for (int n = 0; n < 2; n++) {
        int row = wn * 32 + n * 16 + (lane & 15);
        b1f[n] = ldfrag(B1, row, kc);
        b2f[n] = ldfrag(B2, row, kc);
      }
#pragma unroll
      for (int m = 0; m < 4; m++)
#pragma unroll
        for (int n = 0; n < 2; n++) {
          accA[m][n] = MFMA16(a1f[m], b1f[n], accA[m][n]);
          accB[m][n] = MFMA16(a1f[m], b2f[n], accB[m][n]);
          accB[m][n] = MFMA16(a2f[m], b1f[n], accB[m][n]);
        }
    }
    __syncthreads();
  }
#pragma unroll
  for (int m = 0; m < 4; m++)
#pragma unroll
    for (int n = 0; n < 2; n++)
#pragma unroll
      for (int j = 0; j < 4; j++) {
        int row = m0 + wm * 64 + m * 16 + (lane >> 4) * 4 + j;
        int col = n0 + wn * 32 + n * 16 + (lane & 15);
        dst[(size_t)row * DM + col] = accA[m][n][j] + SPLIT_INV * accB[m][n][j] + bias[col];
      }
}

// ============================================================================
// decoder GEMM: x_recon = z_q(f16) @ dec_w^T(f16) + dec_b, 1-pass f16
// ============================================================================
__global__ __launch_bounds__(512) void k_gdec(const f16* __restrict__ zq16,
                                              const f16* __restrict__ dT,
                                              const float* __restrict__ bias,
                                              float* __restrict__ dst) {
  __shared__ __align__(16) f16 A1[128 * 64], B1[128 * 64];
  int t = threadIdx.x, lane = t & 63, wid = t >> 6;
  int wm = wid >> 2, wn = wid & 3;
  int m0 = blockIdx.y * 128, n0 = blockIdx.x * 128;
  f32x4 acc[4][2] = {};
  int sr = t >> 2, sq = t & 3;

  for (int k0 = 0; k0 < DM; k0 += 64) {
    {
      const f16* s = zq16 + (size_t)(m0 + sr) * DM + k0 + sq * 16;
      stg(A1, sr, 2 * sq, *(const f16x8*)s);
      stg(A1, sr, 2 * sq + 1, *(const f16x8*)(s + 8));
      const f16* sb = dT + (size_t)(n0 + sr) * DM + k0 + sq * 16;
      stg(B1, sr, 2 * sq, *(const f16x8*)sb);
      stg(B1, sr, 2 * sq + 1, *(const f16x8*)(sb + 8));
    }
    __syncthreads();
#pragma unroll
    for (int kk = 0; kk < 2; kk++) {
      f16x8 a1f[4], b1f[2];
      int kc = kk * 4 + (lane >> 4);
#pragma unroll
      for (int m = 0; m < 4; m++) a1f[m] = ldfrag(A1, wm * 64 + m * 16 + (lane & 15), kc);
#pragma unroll
      for (int n = 0; n < 2; n++) b1f[n] = ldfrag(B1, wn * 32 + n * 16 + (lane & 15), kc);
#pragma unroll
      for (int m = 0; m < 4; m++)
#pragma unroll
        for (int n = 0; n < 2; n++) acc[m][n] = MFMA16(a1f[m], b1f[n], acc[m][n]);
    }
    __syncthreads();
  }
#pragma unroll
  for (int m = 0; m < 4; m++)
#pragma unroll
    for (int n = 0; n < 2; n++)
#pragma unroll
      for (int j = 0; j < 4; j++) {
        int row = m0 + wm * 64 + m * 16 + (lane >> 4) * 4 + j;
        int col = n0 + wn * 32 + n * 16 + (lane & 15);
        dst[(size_t)row * DIN + col] = acc[m][n][j] + bias[col];
      }
}

// ============================================================================
// distance + argmin + gather, fused. One block = 128 rows x all 1024 codes.
// ============================================================================
__global__ __launch_bounds__(512) void k_dist(const f16* __restrict__ z1,
                                              const f16* __restrict__ z2,
                                              const f16* __restrict__ e1,
                                              const f16* __restrict__ e2,
                                              const float* __restrict__ enorm,
                                              const float* __restrict__ emb,
                                              float* __restrict__ out,
                                              int* __restrict__ idxws,
                                              int* __restrict__ counts,
                                              float* __restrict__ cacc,
                                              f16* __restrict__ zq16) {
  __shared__ __align__(16) f16 A1[128 * 64], A2[128 * 64], B1[128 * 64], B2[128 * 64];
  __shared__ float enorm_s[KC];
  __shared__ u64 rowmin_s[128];
  __shared__ int idx_s[128];
  __shared__ float red_s[8];
  int t = threadIdx.x, lane = t & 63, wid = t >> 6;
  int wm = wid >> 2, wn = wid & 3;
  int r0 = blockIdx.x * 128;
  int sr = t >> 2, sq = t & 3;

  for (int i = t; i < KC; i += 512) enorm_s[i] = enorm[i];
  if (t < 128) rowmin_s[t] = ~0ull;
  __syncthreads();

  for (int ct = 0; ct < KC / 128; ct++) {
    f32x4 accA[4][2] = {}, accB[4][2] = {};
    int c0 = ct * 128;
    for (int k0 = 0; k0 < DM; k0 += 64) {
      {
        const f16* sa1 = z1 + (size_t)(r0 + sr) * DM + k0 + sq * 16;
        const f16* sa2 = z2 + (size_t)(r0 + sr) * DM + k0 + sq * 16;
        stg(A1, sr, 2 * sq, *(const f16x8*)sa1);
        stg(A1, sr, 2 * sq + 1, *(const f16x8*)(sa1 + 8));
        stg(A2, sr, 2 * sq, *(const f16x8*)sa2);
        stg(A2, sr, 2 * sq + 1, *(const f16x8*)(sa2 + 8));
        const f16* sb1 = e1 + (size_t)(c0 + sr) * DM + k0 + sq * 16;
        const f16* sb2 = e2 + (size_t)(c0 + sr) * DM + k0 + sq * 16;
        stg(B1, sr, 2 * sq, *(const f16x8*)sb1);
        stg(B1, sr, 2 * sq + 1, *(const f16x8*)(sb1 + 8));
        stg(B2, sr, 2 * sq, *(const f16x8*)sb2);
        stg(B2, sr, 2 * sq + 1, *(const f16x8*)(sb2 + 8));
      }
      __syncthreads();
#pragma unroll
      for (int kk = 0; kk < 2; kk++) {
        f16x8 a1f[4], a2f[4], b1f[2], b2f[2];
        int kc = kk * 4 + (lane >> 4);
#pragma unroll
        for (int m = 0; m < 4; m++) {
          int row = wm * 64 + m * 16 + (lane & 15);
          a1f[m] = ldfrag(A1, row, kc);
          a2f[m] = ldfrag(A2, row, kc);
        }
#pragma unroll
        for (int n = 0; n < 2; n++) {
          int row = wn * 32 + n * 16 + (lane & 15);
          b1f[n] = ldfrag(B1, row, kc);
          b2f[n] = ldfrag(B2, row, kc);
        }
#pragma unroll
        for (int m = 0; m < 4; m++)
#pragma unroll
          for (int n = 0; n < 2; n++) {
            accA[m][n] = MFMA16(a1f[m], b1f[n], accA[m][n]);
            accB[m][n] = MFMA16(a1f[m], b2f[n], accB[m][n]);
            accB[m][n] = MFMA16(a2f[m], b1f[n], accB[m][n]);
          }
      }
      __syncthreads();
    }
#pragma unroll
    for (int m = 0; m < 4; m++)
#pragma unroll
      for (int j = 0; j < 4; j++) {
        int r_l = wm * 64 + m * 16 + (lane >> 4) * 4 + j;
        u64 best = ~0ull;
#pragma unroll
        for (int n = 0; n < 2; n++) {
          int col = c0 + wn * 32 + n * 16 + (lane & 15);
          float dot = accA[m][n][j] + SPLIT_INV * accB[m][n][j];
          float s = fmaf(-2.0f, dot, enorm_s[col]);
          u32 kb = __float_as_uint(s);
          kb = (kb & 0x80000000u) ? ~kb : (kb | 0x80000000u);
          u64 p = ((u64)kb << 32) | (u32)col;
          best = p < best ? p : best;
        }
#pragma unroll
        for (int msk = 1; msk < 16; msk <<= 1) {
          u64 o = __shfl_xor(best, msk, 64);
          best = o < best ? o : best;
        }
        if ((lane & 15) == 0) atomicMin(&rowmin_s[r_l], best);
      }
    __syncthreads();
  }

  if (t < 128) {
    int idx = (int)(u32)(rowmin_s[t] & 0xffffffffull);
    int R = r0 + t;
    out[OFF_IDX + R] = (float)idx;
    idxws[R] = idx;
    atomicAdd(counts + idx, 1);
    idx_s[t] = idx;
  }
  __syncthreads();
  float loc = 0.f;
  {
    int r = t >> 2, q = t & 3;
    int R = r0 + r;
    int idx = idx_s[r];
    const float* e = emb + (size_t)idx * DM + q * 128;
    const float* z = out + OFF_ZE + (size_t)R * DM + q * 128;
    float* zq = out + OFF_ZQ + (size_t)R * DM + q * 128;
    f16* zp = zq16 + (size_t)R * DM + q * 128;
    for (int i = 0; i < 128; i += 4) {
      float4 ev = *(const float4*)(e + i);
      float a[4] = {ev.x, ev.y, ev.z, ev.w};
#pragma unroll
      for (int jj = 0; jj < 4; jj++) {
        zq[i + jj] = a[jj];
        zp[i + jj] = (f16)a[jj];
        float d = z[i + jj] - a[jj];
        loc = fmaf(d, d, loc);
      }
    }
  }
#pragma unroll
  for (int m = 1; m < 64; m <<= 1) loc += __shfl_xor(loc, m, 64);
  if (lane == 0) red_s[wid] = loc;
  __syncthreads();
  if (t == 0) {
    float s = 0.f;
#pragma unroll
    for (int i = 0; i < 8; i++) s += red_s[i];
    atomicAdd(cacc, s);
  }
}

// ============================================================================
// LayerNorm (wave per row) + f16 split planes of z_e
// ============================================================================
__global__ __launch_bounds__(256) void k_ln2(float* __restrict__ ze,
                                             const float* __restrict__ g,
                                             const float* __restrict__ b,
                                             f16* __restrict__ z1,
                                             f16* __restrict__ z2) {
  int t = threadIdx.x, lane = t & 63, wid = t >> 6;
  int R = blockIdx.x * 4 + wid;
  float* row = ze + (size_t)R * DM;
  float v[8];
  float s = 0.f, sq = 0.f;
#pragma unroll
  for (int j = 0; j < 8; j++) {
    v[j] = row[lane + j * 64];
    s += v[j];
    sq = fmaf(v[j], v[j], sq);
  }
#pragma unroll
  for (int m = 1; m < 64; m <<= 1) {
    s += __shfl_xor(s, m, 64);
    sq += __shfl_xor(sq, m, 64);
  }
  float mu = s * (1.f / DM);
  float var = sq * (1.f / DM) - mu * mu;
  float rs = rsqrtf(var + 1e-5f);
#pragma unroll
  for (int j = 0; j < 8; j++) {
    int c = lane + j * 64;
    float o = (v[j] - mu) * rs * g[c] + b[c];
    row[c] = o;
    f16 h = (f16)o;
    z1[(size_t)R * DM + c] = h;
    z2[(size_t)R * DM + c] = (f16)((o - (float)h) * SPLIT_SC);
  }
}

// ============================================================================
// EMA tail: scan + chunk descriptors (balanced segment-sum)
// ============================================================================
__global__ __launch_bounds__(1024) void k_scan(const int* __restrict__ counts,
                                               const float* __restrict__ cs_in,
                                               float* __restrict__ out,
                                               int* __restrict__ starts,
                                               int* __restrict__ offw,
                                               float* __restrict__ csd,
                                               const float* __restrict__ cacc,
                                               int* __restrict__ chpfx,
                                               int* __restrict__ chcode) {
  __shared__ float f[1024];
  __shared__ int ib[1024];
  int t = threadIdx.x;
  int cnt = counts[t];
  float ncs = 0.99f * cs_in[t] + 0.01f * (float)cnt;
  out[OFF_NCS + t] = ncs;
  f[t] = ncs;
  __syncthreads();
  for (int s = 512; s > 0; s >>= 1) {
    if (t < s) f[t] += f[t + s];
    __syncthreads();
  }
  float n = f[0];
  csd[t] = (ncs + 1e-5f) / (n + (float)KC * 1e-5f) * n;
  ib[t] = cnt;
  __syncthreads();
  for (int s = 1; s < 1024; s <<= 1) {          // Hillis-Steele inclusive scan
    int y = (t >= s) ? ib[t - s] : 0;
    __syncthreads();
    ib[t] += y;
    __syncthreads();
  }
  int excl = ib[t] - cnt;
  starts[t] = excl;
  offw[t] = excl;
  if (t == 0) out[OFF_CL] = cacc[0] * (1.f / ((float)NROWS * (float)DM));
  // second scan: chunk counts -> chunk prefix + chunk->code map
  int nch = (cnt + CHSZ - 1) / CHSZ;
  __syncthreads();
  ib[t] = nch;
  __syncthreads();
  for (int s = 1; s < 1024; s <<= 1) {
    int y = (t >= s) ? ib[t - s] : 0;
    __syncthreads();
    ib[t] += y;
    __syncthreads();
  }
  int chx = ib[t] - nch;
  chpfx[t] = chx;
  if (t == KC - 1) chpfx[KC] = ib[t];
  for (int j = 0; j < nch; j++) chcode[chx + j] = t;
}

__global__ __launch_bounds__(256) void k_scatter(const int* __restrict__ idxws,
                                                 int* __restrict__ offw,
                                                 int* __restrict__ rowlist) {
  int r = blockIdx.x * 256 + threadIdx.x;
  int idx = idxws[r];
  int pos = atomicAdd(offw + idx, 1);
  rowlist[pos] = r;
}

// one block per chunk: fp32 partial sum of <=CHSZ rows of one code (deterministic)
__global__ __launch_bounds__(128) void k_partsum(const int* __restrict__ chpfx,
                                                 const int* __restrict__ chcode,
                                                 const int* __restrict__ starts,
                                                 const int* __restrict__ counts,
                                                 const int* __restrict__ rowlist,
                                                 const float* __restrict__ out,
                                                 float* __restrict__ part) {
  int c = blockIdx.x, t = threadIdx.x;
  if (c >= chpfx[KC]) return;
  int code = chcode[c];
  int j = c - chpfx[code];
  int ofs = starts[code] + j * CHSZ;
  int len = min(CHSZ, counts[code] - j * CHSZ);
  __shared__ int rl[CHSZ];
  if (t < len) rl[t] = rowlist[ofs + t];
  __syncthreads();
  const float* zeb = out + OFF_ZE;
  float a0 = 0.f, a1 = 0.f, a2 = 0.f, a3 = 0.f;
  for (int i = 0; i < len; i++) {
    const float* z = zeb + (size_t)rl[i] * DM;
    a0 += z[t];
    a1 += z[t + 128];
    a2 += z[t + 256];
    a3 += z[t + 384];
  }
  float* p = part + (size_t)c * DM;
  p[t] = a0;
  p[t + 128] = a1;
  p[t + 256] = a2;
  p[t + 384] = a3;
}

// per code: ordered sum of its chunk partials + EMA epilogue (deterministic)
__global__ __launch_bounds__(128) void k_codesum2(const int* __restrict__ chpfx,
                                                  const float* __restrict__ part,
                                                  const float* __restrict__ ema_in,
                                                  const float* __restrict__ csd,
                                                  float* __restrict__ out) {
  int k = blockIdx.x, t = threadIdx.x;
  int base = chpfx[k], nch = chpfx[k + 1] - base;
  float a0 = 0.f, a1 = 0.f, a2 = 0.f, a3 = 0.f;
  for (int i = 0; i < nch; i++) {
    const float* p = part + (size_t)(base + i) * DM;
    a0 += p[t];
    a1 += p[t + 128];
    a2 += p[t + 256];
    a3 += p[t + 384];
  }
  float cs = csd[k];
  float sum[4] = {a0, a1, a2, a3};
#pragma unroll
  for (int j = 0; j < 4; j++) {
    int c = t + j * 128;
    float e = 0.99f * ema_in[(size_t)k * DM + c] + 0.01f * sum[j];
    out[OFF_NEMA + (size_t)k * DM + c] = e;
    out[OFF_NE + (size_t)k * DM + c] = e / cs;
  }
}

// ============================================================================
// fallback path kernels (round-1, proven)
// ============================================================================
__global__ __launch_bounds__(256) void k_init(u64* __restrict__ rowmin,
                                              int* __restrict__ counts,
                                              float* __restrict__ cacc) {
  int i = blockIdx.x * 256 + threadIdx.x;
  rowmin[i] = ~0ull;
  if (i < KC) counts[i] = 0;
  if (i == 0) cacc[0] = 0.f;
}

__global__ __launch_bounds__(256) void k_transpose(const float* __restrict__ E,
                                                   float* __restrict__ ET) {
  __shared__ float tile[32][33];
  int tx = threadIdx.x & 31;
  int ty = threadIdx.x >> 5;
  int kb = blockIdx.y * 32;
  int db = blockIdx.x * 32;
#pragma unroll
  for (int i = 0; i < 32; i += 8)
    tile[ty + i][tx] = E[(size_t)(kb + ty + i) * DM + db + tx];
  __syncthreads();
#pragma unroll
  for (int i = 0; i < 32; i += 8)
    ET[(size_t)(db + ty + i) * KC + kb + tx] = tile[tx][ty + i];
}

template <int EPI>
__global__ __launch_bounds__(256) void k_gemm(
    const float* __restrict__ A, int lda,
    const float* __restrict__ B, int ldb,
    const float* __restrict__ bias,
    float* __restrict__ C, int ldc,
    const float* __restrict__ znorm,
    u64* __restrict__ rowmin,
    int K) {
  __shared__ float As[16][132];
  __shared__ float Bs[16][132];
  const int t = threadIdx.x;
  const int tx = t & 15, ty = t >> 4;
  const int rowBase = blockIdx.y * 128;
  const int colBase = blockIdx.x * 128;
  float acc[8][8];
#pragma unroll
  for (int i = 0; i < 8; i++)
#pragma unroll
    for (int j = 0; j < 8; j++) acc[i][j] = 0.f;
  for (int k0 = 0; k0 < K; k0 += 16) {
#pragma unroll
    for (int jj = 0; jj < 8; jj++) {
      int e = t + 256 * jj;
      int row = e >> 4, kk = e & 15;
      As[kk][row] = A[(size_t)(rowBase + row) * lda + k0 + kk];
    }
#pragma unroll
    for (int jj = 0; jj < 2; jj++) {
      int e = t + 256 * jj;
      int row = e >> 5, c4 = (e & 31) << 2;
      float4 v = *reinterpret_cast<const float4*>(B + (size_t)(k0 + row) * ldb + colBase + c4);
      *reinterpret_cast<float4*>(&Bs[row][c4]) = v;
    }
    __syncthreads();
#pragma unroll
    for (int k = 0; k < 16; k++) {
      float4 a0 = *reinterpret_cast<const float4*>(&As[k][ty * 4]);
      float4 a1 = *reinterpret_cast<const float4*>(&As[k][ty * 4 + 64]);
      float4 b0 = *reinterpret_cast<const float4*>(&Bs[k][tx * 4]);
      float4 b1 = *reinterpret_cast<const float4*>(&Bs[k][tx * 4 + 64]);
      float av[8] = {a0.x, a0.y, a0.z, a0.w, a1.x, a1.y, a1.z, a1.w};
      float bv[8] = {b0.x, b0.y, b0.z, b0.w, b1.x, b1.y, b1.z, b1.w};
#pragma unroll
      for (int i = 0; i < 8; i++)
#pragma unroll
        for (int j = 0; j < 8; j++)
          acc[i][j] = fmaf(av[i], bv[j], acc[i][j]);
    }
    __syncthreads();
  }
  if (EPI == 0) {
#pragma unroll
    for (int ib = 0; ib < 2; ib++)
#pragma unroll
      for (int i = 0; i < 4; i++) {
        size_t r = rowBase + ty * 4 + ib * 64 + i;
#pragma unroll
        for (int jb = 0; jb < 2; jb++)
#pragma unroll
          for (int j = 0; j < 4; j++) {
            int c = colBase + tx * 4 + jb * 64 + j;
            C[r * ldc + c] = acc[ib * 4 + i][jb * 4 + j] + bias[c];
          }
      }
  } else {
    float en[8];
#pragma unroll
    for (int jb = 0; jb < 2; jb++)
#pragma unroll
      for (int j = 0; j < 4; j++)
        en[jb * 4 + j] = bias[colBase + tx * 4 + jb * 64 + j];
#pragma unroll
    for (int ib = 0; ib < 2; ib++)
#pragma unroll
      for (int i = 0; i < 4; i++) {
        int r = rowBase + ty * 4 + ib * 64 + i;
        float zn = znorm[r];
        u64 best = ~0ull;
#pragma unroll
        for (int jb = 0; jb < 2; jb++)
#pragma unroll
          for (int j = 0; j < 4; j++) {
            int c = colBase + tx * 4 + jb * 64 + j;
            float t1 = fmaf(-2.0f, acc[ib * 4 + i][jb * 4 + j], zn);
            float d = t1 + en[jb * 4 + j];
            u32 kb = __float_as_uint(d);
            kb = (kb & 0x80000000u) ? ~kb : (kb | 0x80000000u);
            u64 p = ((u64)kb << 32) | (u32)c;
            best = p < best ? p : best;
          }
#pragma unroll
        for (int m = 1; m < 16; m <<= 1) {
          u64 o = __shfl_xor(best, m, 64);
          best = o < best ? o : best;
        }
        if (tx == 0) atomicMin(rowmin + r, best);
      }
  }
}

__global__ __launch_bounds__(128) void k_ln(float* __restrict__ ze,
                                            const float* __restrict__ g,
                                            const float* __restrict__ b,
                                            float* __restrict__ znorm) {
  int r = blockIdx.x, t = threadIdx.x;
  float* row = ze + (size_t)r * DM;
  float v[4];
  float s = 0.f, sq = 0.f;
#pragma unroll
  for (int j = 0; j < 4; j++) {
    v[j] = row[t + j * 128];
    s += v[j];
    sq = fmaf(v[j], v[j], sq);
  }
#pragma unroll
  for (int m = 1; m < 64; m <<= 1) {
    s += __shfl_xor(s, m, 64);
    sq += __shfl_xor(sq, m, 64);
  }
  __shared__ float sh[4];
  if ((t & 63) == 0) { sh[(t >> 6) * 2] = s; sh[(t >> 6) * 2 + 1] = sq; }
  __syncthreads();
  s = sh[0] + sh[2];
  sq = sh[1] + sh[3];
  float mu = s * (1.f / DM);
  float var = sq * (1.f / DM) - mu * mu;
  float rs = rsqrtf(var + 1e-5f);
  float zn = 0.f;
#pragma unroll
  for (int j = 0; j < 4; j++) {
    int c = t + j * 128;
    float o = (v[j] - mu) * rs * g[c] + b[c];
    row[c] = o;
    zn = fmaf(o, o, zn);
  }
#pragma unroll
  for (int m = 1; m < 64; m <<= 1) zn += __shfl_xor(zn, m, 64);
  __syncthreads();
  if ((t & 63) == 0) sh[t >> 6] = zn;
  __syncthreads();
  if (t == 0) znorm[r] = sh[0] + sh[1];
}

__global__ __launch_bounds__(128) void k_gather(const u64* __restrict__ rowmin,
                                                const float* __restrict__ E,
                                                float* __restrict__ out,
                                                int* __restrict__ idxws,
                                                int* __restrict__ counts,
                                                float* __restrict__ cacc) {
  int r = blockIdx.x, t = threadIdx.x;
  int idx = (int)(u32)(rowmin[r] & 0xffffffffull);
  const float* ze = out + OFF_ZE + (size_t)r * DM;
  float* zq = out + OFF_ZQ + (size_t)r * DM;
  const float* e = E + (size_t)idx * DM;
  float loc = 0.f;
#pragma unroll
  for (int j = 0; j < 4; j++) {
    int c = t + j * 128;
    float z = ze[c], q = e[c];
    zq[c] = q;
    float d = z - q;
    loc = fmaf(d, d, loc);
  }
#pragma unroll
  for (int m = 1; m < 64; m <<= 1) loc += __shfl_xor(loc, m, 64);
  __shared__ float sh[2];
  if ((t & 63) == 0) sh[t >> 6] = loc;
  __syncthreads();
  if (t == 0) {
    atomicAdd(cacc, sh[0] + sh[1]);
    atomicAdd(counts + idx, 1);
    out[OFF_IDX + r] = (float)idx;
    idxws[r] = idx;
  }
}

// ============================================================================
extern "C" void kernel_launch(void* const* d_in, const int* in_sizes, int n_in,
                              void* d_out, int out_size, void* d_ws, size_t ws_size,
                              hipStream_t stream) {
  (void)in_sizes; (void)n_in; (void)out_size;
  const float* x = (const float*)d_in[0];
  const float* enc_w = (const float*)d_in[1];
  const float* enc_b = (const float*)d_in[2];
  const float* ln_g = (const float*)d_in[3];
  const float* ln_b = (const float*)d_in[4];
  const float* dec_w = (const float*)d_in[5];
  const float* dec_b = (const float*)d_in[6];
  const float* emb = (const float*)d_in[7];
  const float* cs_in = (const float*)d_in[8];
  const float* ema_in = (const float*)d_in[9];
  float* out = (float*)d_out;
  char* ws = (char*)d_ws;
  int* idxws = (int*)(ws + WS_IDX);
  int* counts = (int*)(ws + WS_COUNTS);
  int* starts = (int*)(ws + WS_STARTS);
  int* offw = (int*)(ws + WS_OFFW);
  int* rowlist = (int*)(ws + WS_ROWLIST);
  float* csd = (float*)(ws + WS_CSD);
  float* cacc = (float*)(ws + WS_CACC);
  float* enorm = (float*)(ws + WS_ENORM);

  if (ws_size >= WS2_NEED + (8ull << 20)) {
    // ---- MFMA path ----
    f16* zq16 = (f16*)(ws + WS2_ZQ16);
    f16* wt1 = (f16*)(ws + WS2_WT1);
    f16* wt2 = (f16*)(ws + WS2_WT2);
    f16* dT = (f16*)(ws + WS2_DT);
    f16* e1 = (f16*)(ws + WS2_E1);
    f16* e2 = (f16*)(ws + WS2_E2);
    int* chpfx = (int*)(ws + WS3_CHPFX);
    int* chcode = (int*)(ws + WS3_CHCODE);
    float* part = (float*)(ws + WS3_PART);
    f16* z1 = (f16*)out;                 // scratch in x_recon region (overwritten by k_gdec)
    f16* z2 = z1 + (size_t)NROWS * DM;

    k_init2<<<dim3(4), dim3(256), 0, stream>>>(counts, cacc);
    k_prept<<<dim3(16, 32), dim3(256), 0, stream>>>(enc_w, wt1, wt2, DIN, DM);
    k_prept<<<dim3(32, 16), dim3(256), 0, stream>>>(dec_w, dT, nullptr, DM, DIN);
    k_prepe<<<dim3(512), dim3(256), 0, stream>>>(emb, e1, e2);
    k_enorm<<<dim3(KC), dim3(64), 0, stream>>>(emb, enorm);
    k_genc<<<dim3(4, 256), dim3(512), 0, stream>>>(x, wt1, wt2, enc_b, out + OFF_ZE);
    k_ln2<<<dim3(8192), dim3(256), 0, stream>>>(out + OFF_ZE, ln_g, ln_b, z1, z2);
    k_dist<<<dim3(256), dim3(512), 0, stream>>>(z1, z2, e1, e2, enorm, emb, out,
                                                idxws, counts, cacc, zq16);
    k_scan<<<dim3(1), dim3(1024), 0, stream>>>(counts, cs_in, out, starts, offw, csd,
                                               cacc, chpfx, chcode);
    k_scatter<<<dim3(128), dim3(256), 0, stream>>>(idxws, offw, rowlist);
    k_partsum<<<dim3(MAXCH), dim3(128), 0, stream>>>(chpfx, chcode, starts, counts,
                                                     rowlist, out, part);
    k_codesum2<<<dim3(KC), dim3(128), 0, stream>>>(chpfx, part, ema_in, csd, out);
    k_gdec<<<dim3(8, 256), dim3(512), 0, stream>>>(zq16, dT, dec_b, out + OFF_XR);
  } else {
    // ---- fallback: round-1 fp32 path (uses its own serial codesum-free tail) ----
    float* embT = (float*)(ws + WS_EMBT);
    u64* rowmin = (u64*)(ws + WS_ROWMIN);
    float* znorm = (float*)(ws + WS_ZNORM);
    int* chpfx = (int*)(ws + WS_CSD);      // unused sizes ok; reuse low region
    (void)chpfx;
    k_init<<<dim3(NROWS / 256), dim3(256), 0, stream>>>(rowmin, counts, cacc);
    k_transpose<<<dim3(DM / 32, KC / 32), dim3(256), 0, stream>>>(emb, embT);
    k_enorm<<<dim3(KC), dim3(64), 0, stream>>>(emb, enorm);
    k_gemm<0><<<dim3(DM / 128, NROWS / 128), dim3(256), 0, stream>>>(
        x, DIN, enc_w, DM, enc_b, out + OFF_ZE, DM, nullptr, nullptr, DIN);
    k_ln<<<dim3(NROWS), dim3(128), 0, stream>>>(out + OFF_ZE, ln_g, ln_b, znorm);
    k_gemm<1><<<dim3(KC / 128, NROWS / 128), dim3(256), 0, stream>>>(
        out + OFF_ZE, DM, embT, KC, enorm, nullptr, 0, znorm, rowmin, DM);
    k_gather<<<dim3(NROWS), dim3(128), 0, stream>>>(rowmin, emb, out, idxws, counts, cacc);
    // reuse chunked tail for balance on fallback too
    int* chpfx2 = (int*)(ws + WS_STARTS);  // NOTE: fallback keeps old behavior below
    (void)chpfx2;
    k_scan<<<dim3(1), dim3(1024), 0, stream>>>(counts, cs_in, out, starts, offw, csd,
                                               cacc, (int*)(ws + WS_EMBT),
                                               (int*)(ws + WS_EMBT + 8192));
    k_scatter<<<dim3(NROWS / 256), dim3(256), 0, stream>>>(idxws, offw, rowlist);
    k_partsum<<<dim3(MAXCH), dim3(128), 0, stream>>>((int*)(ws + WS_EMBT),
                                                     (int*)(ws + WS_EMBT + 8192),
                                                     starts, counts, rowlist, out,
                                                     (float*)(ws + WS_EMBT + 65536));
    k_codesum2<<<dim3(KC), dim3(128), 0, stream>>>((int*)(ws + WS_EMBT),
                                                   (float*)(ws + WS_EMBT + 65536),
                                                   ema_in, csd, out);
    k_gemm<0><<<dim3(DIN / 128, NROWS / 128), dim3(256), 0, stream>>>(
        out + OFF_ZQ, DM, dec_w, DIN, dec_b, out + OFF_XR, DIN, nullptr, nullptr, DM);
  }
}